// Round 17
// baseline (198.238 us; speedup 1.0000x reference)
//
#include <hip/hip_runtime.h>
#include <hip/hip_bf16.h>
#include <stdint.h>

typedef int i32x4 __attribute__((ext_vector_type(4)));

constexpr int IN_F = 1024;
constexpr int OUT_F = 1024;
constexpr int M_TOT = 8 * 4096;   // 32768 tokens
constexpr int K_TOT = 1024;
constexpr int N_TOT = 1024;

// ---------------- kernel 1: unpack ternary weights (bit-plane permuted) -> int8 ----------------
__global__ __launch_bounds__(256) void unpack_kernel(
    const int* __restrict__ packed,
    int8_t* __restrict__ wt)           // [OUT_F][IN_F] int8 in {-1,0,1} (B^T layout)
{
    const int o = blockIdx.x;
    const int k0 = threadIdx.x * 4;
    const int sh = (o >> 8) * 2;
    const int pbase = ((o & 255) << 10) + k0;
    const int4 pw = *reinterpret_cast<const int4*>(packed + pbase);
    char4 r;
    r.x = (char)(((pw.x >> sh) & 3) - 1);
    r.y = (char)(((pw.y >> sh) & 3) - 1);
    r.z = (char)(((pw.z >> sh) & 3) - 1);
    r.w = (char)(((pw.w >> sh) & 3) - 1);
    *reinterpret_cast<char4*>(wt + (size_t)o * IN_F + k0) = r;
}

// ---------------- kernel 2: FUSED max + quantize-on-stage + int8 MFMA GEMM ----------------
// r16 GEMM core (256x256, BK=128, 8 waves 2Mx4N, dbuf, involution swizzle, plain stores).
// NEW: q never touches memory. Per block:
//   max-phase: row absmax of own 256-row x panel (1 MiB; 4 same-tm siblings are
//   XCD-adjacent under the swizzle -> L2 absorbs redundancy) -> sAs/sInv in LDS.
//   K-loop A-staging: load x f32 (linear) -> quantize in-reg (mul/rndne/cvt; clamp
//   provably dead: |x*as| <= 127 by construction) -> pack -> ds_write_b128 at the
//   swizzled position (write-side XOR, same involution; conflict-free 128B rows).
//   B staging unchanged (global_load_lds from unpacked wt).
// Sync per tile: per-phase lgkmcnt(0) (r5-proven), vmcnt(0)+barrier at end (covers B;
// x loads are register-carried -> compiler auto-waits). No cross-block anything.
constexpr int BM = 256, BN = 256, BK = 128;
constexpr int NT = K_TOT / BK;   // 8

__global__ __launch_bounds__(512, 2) void fused_kernel(
    const float* __restrict__ x,
    const int8_t* __restrict__ wb,
    const float* __restrict__ wscale,
    const float* __restrict__ bias,
    float* __restrict__ out)
{
    // XCD-aware swizzle: nwg = 512, divisible by 8 -> bijective simple remap
    int bid = blockIdx.x;
    bid = (bid & 7) * ((int)gridDim.x >> 3) + (bid >> 3);
    const int tm = bid >> 2;            // 0..127
    const int tn = bid & 3;             // 0..3

    const int tid = threadIdx.x;
    const int lane = tid & 63;
    const int wid = tid >> 6;           // 0..7
    const int wr = wid >> 2;            // 0..1 (M half)
    const int wc = wid & 3;             // 0..3 (N quarter)

    __shared__ int8_t lds[2][2][2][128 * 128];  // [buf][ab][region] = 128 KiB
    __shared__ float sAs[256];                   // 127/a per block row
    __shared__ float sInv[256];                  // a/127*wsc per block row

    const int rowA0 = tm * BM;
    const int rowB0 = tn * BN;
    const int frow = lane & 15;
    const int fq = lane >> 4;

    // ======== max-phase: 4 passes x 64 rows, 8 lanes/row (128B segments) ========
    {
        const float wsc = wscale[0];
        const int c8 = lane & 7;
        #pragma unroll 1
        for (int pass = 0; pass < 4; ++pass) {
            const int lr = pass * 64 + wid * 8 + (lane >> 3);
            const float4* xr = reinterpret_cast<const float4*>(x + (size_t)(rowA0 + lr) * IN_F);
            float m = 0.f;
            #pragma unroll 8
            for (int j = 0; j < 32; ++j) {
                const float4 v = xr[c8 + 8 * j];
                m = fmaxf(m, fmaxf(fmaxf(fabsf(v.x), fabsf(v.y)),
                                   fmaxf(fabsf(v.z), fabsf(v.w))));
            }
            m = fmaxf(m, __shfl_xor(m, 1));
            m = fmaxf(m, __shfl_xor(m, 2));
            m = fmaxf(m, __shfl_xor(m, 4));
            if (c8 == 0) {
                const float a = fmaxf(m, 1e-5f);
                sAs[lr] = 127.0f / a;
                sInv[lr] = (a / 127.0f) * wsc;
            }
        }
    }
    __syncthreads();

    // ======== staging machinery ========
    const int rl0 = tid >> 3;           // 0..63
    const int cc = tid & 7;             // linear 16B chunk within BK
    const int pz = cc ^ (rl0 & 7);      // swizzled chunk position for writes

    float asv[2][2];
    #pragma unroll
    for (int r = 0; r < 2; ++r)
        #pragma unroll
        for (int j = 0; j < 2; ++j)
            asv[r][j] = sAs[r * 64 + j * 128 + rl0];

    float4 xr0[2][4], xr1[2][4];
    // A source rows: region r, j -> block row r*64 + j*128 + rl0 (r16 region map)
    auto xload = [&](int region, int kt, float4 (&xr)[2][4]) {
        #pragma unroll
        for (int j = 0; j < 2; ++j) {
            const float* src = x + (size_t)(rowA0 + region * 64 + j * 128 + rl0) * IN_F
                                 + kt * BK + cc * 16;
            #pragma unroll
            for (int u = 0; u < 4; ++u)
                xr[j][u] = reinterpret_cast<const float4*>(src)[u];
        }
    };
    auto qwrite = [&](int buf, int region, const float4 (&xr)[2][4]) {
        #pragma unroll
        for (int j = 0; j < 2; ++j) {
            const float as = asv[region][j];
            i32x4 o4;
            #pragma unroll
            for (int u = 0; u < 4; ++u) {
                const float4 v = xr[j][u];
                const int b0 = (int)rintf(v.x * as) & 255;
                const int b1 = (int)rintf(v.y * as) & 255;
                const int b2 = (int)rintf(v.z * as) & 255;
                const int b3 = (int)rintf(v.w * as) & 255;
                o4[u] = b0 | (b1 << 8) | (b2 << 16) | (b3 << 24);
            }
            *reinterpret_cast<i32x4*>(
                &lds[buf][0][region][((j * 64 + rl0) * 8 + pz) * 16]) = o4;
        }
    };
    auto stageB = [&](int buf, int region, int kt) {
        #pragma unroll
        for (int j = 0; j < 2; ++j) {
            const int c = j * 512 + tid;
            const int rl = c >> 3, ccb = c & 7;
            const int grow = rowB0 + region * 128 + rl;
            const int scc = ccb ^ (rl & 7);
            const int8_t* src = wb + (size_t)grow * K_TOT + kt * BK + scc * 16;
            __builtin_amdgcn_global_load_lds(
                (const __attribute__((address_space(1))) void*)src,
                (__attribute__((address_space(3))) void*)&lds[buf][1][region][c * 16],
                16, 0, 0);
        }
    };

    auto ldA = [&](int buf, int region, int mf, int ks) -> i32x4 {
        const int local = wr * 64 + (mf & 3) * 16 + frow;
        const int ch = (ks * 4 + fq) ^ (local & 7);
        return *reinterpret_cast<const i32x4*>(&lds[buf][0][region][local * 128 + ch * 16]);
    };
    auto ldB = [&](int buf, int nf, int ks) -> i32x4 {
        const int region = wc >> 1;
        const int local = (wc & 1) * 64 + nf * 16 + frow;
        const int ch = (ks * 4 + fq) ^ (local & 7);
        return *reinterpret_cast<const i32x4*>(&lds[buf][1][region][local * 128 + ch * 16]);
    };

    i32x4 acc[8][4] = {};
    i32x4 aF[4][2], bF[4][2], aG[4][2];

    // prologue: tile 0 -> buf 0
    xload(0, 0, xr0);
    stageB(0, 0, 0); stageB(0, 1, 0);
    qwrite(0, 0, xr0);                  // compiler auto-waits xr0
    xload(1, 0, xr1);
    qwrite(0, 1, xr1);
    asm volatile("s_waitcnt lgkmcnt(0)" ::: "memory");   // my ds_writes done
    asm volatile("s_waitcnt vmcnt(0)" ::: "memory");     // my B stages landed
    __builtin_amdgcn_s_barrier();

    #pragma unroll 1
    for (int T = 0; T < NT; ++T) {
        const int cur = T & 1, nxt = cur ^ 1;
        const bool st = (T + 1 < NT);

        if (st) {
            xload(0, T + 1, xr0);
            stageB(nxt, 0, T + 1); stageB(nxt, 1, T + 1);
        }

        // ---- Ph0: read A-R0 + B; MFMA rows-lo (32)
        #pragma unroll
        for (int mf = 0; mf < 4; ++mf)
            #pragma unroll
            for (int ks = 0; ks < 2; ++ks)
                aF[mf][ks] = ldA(cur, 0, mf, ks);
        #pragma unroll
        for (int nf = 0; nf < 4; ++nf)
            #pragma unroll
            for (int ks = 0; ks < 2; ++ks)
                bF[nf][ks] = ldB(cur, nf, ks);
        asm volatile("s_waitcnt lgkmcnt(0)" ::: "memory");
        __builtin_amdgcn_sched_barrier(0);
        __builtin_amdgcn_s_setprio(1);
        #pragma unroll
        for (int mf = 0; mf < 4; ++mf)
            #pragma unroll
            for (int nf = 0; nf < 4; ++nf)
                #pragma unroll
                for (int ks = 0; ks < 2; ++ks)
                    acc[mf][nf] = __builtin_amdgcn_mfma_i32_16x16x64_i8(
                        aF[mf][ks], bF[nf][ks], acc[mf][nf], 0, 0, 0);
        __builtin_amdgcn_s_setprio(0);

        if (st) {
            qwrite(nxt, 0, xr0);        // region 0 of T+1 (buf nxt: freed at T-1 barrier)
            xload(1, T + 1, xr1);
        }

        // ---- Ph1: read A-R1; MFMA rows-hi (32)
        #pragma unroll
        for (int mf = 0; mf < 4; ++mf)
            #pragma unroll
            for (int ks = 0; ks < 2; ++ks)
                aG[mf][ks] = ldA(cur, 1, mf, ks);
        asm volatile("s_waitcnt lgkmcnt(0)" ::: "memory");
        __builtin_amdgcn_sched_barrier(0);
        __builtin_amdgcn_s_setprio(1);
        #pragma unroll
        for (int mf = 0; mf < 4; ++mf)
            #pragma unroll
            for (int nf = 0; nf < 4; ++nf)
                #pragma unroll
                for (int ks = 0; ks < 2; ++ks)
                    acc[4 + mf][nf] = __builtin_amdgcn_mfma_i32_16x16x64_i8(
                        aG[mf][ks], bF[nf][ks], acc[4 + mf][nf], 0, 0, 0);
        __builtin_amdgcn_s_setprio(0);

        if (st) {
            qwrite(nxt, 1, xr1);
            asm volatile("s_waitcnt lgkmcnt(0)" ::: "memory");  // my ds_writes done
            asm volatile("s_waitcnt vmcnt(0)" ::: "memory");    // my B stages landed
            __builtin_amdgcn_s_barrier();                       // buf nxt published
        }
    }

    // epilogue: C/D 16x16 layout (col = lane&15, row = fq*4 + reg); plain stores.
    #pragma unroll
    for (int mi = 0; mi < 8; ++mi) {
        #pragma unroll
        for (int j = 0; j < 4; ++j) {
            const int lrow = wr * 128 + mi * 16 + fq * 4 + j;
            const int gm = rowA0 + lrow;
            const float sc = sInv[lrow];
            #pragma unroll
            for (int nf = 0; nf < 4; ++nf) {
                const int gn = rowB0 + wc * 64 + nf * 16 + frow;
                out[(size_t)gm * N_TOT + gn] = (float)acc[mi][nf][j] * sc + bias[gn];
            }
        }
    }
}

extern "C" void kernel_launch(void* const* d_in, const int* in_sizes, int n_in,
                              void* d_out, int out_size, void* d_ws, size_t ws_size,
                              hipStream_t stream) {
    const float* x = (const float*)d_in[0];
    const int* packed = (const int*)d_in[1];
    const float* wscale = (const float*)d_in[2];
    const float* bias = (const float*)d_in[3];
    float* out = (float*)d_out;

    int8_t* wt = (int8_t*)d_ws;   // 1 MiB unpacked ternary weights

    unpack_kernel<<<OUT_F, 256, 0, stream>>>(packed, wt);
    fused_kernel<<<(M_TOT / BM) * (N_TOT / BN), 512, 0, stream>>>(
        x, wt, wscale, bias, out);
}

// Round 18
// 146.136 us; speedup vs baseline: 1.3565x; 1.3565x over previous
//
#include <hip/hip_runtime.h>
#include <hip/hip_bf16.h>
#include <stdint.h>

typedef int i32x4 __attribute__((ext_vector_type(4)));

constexpr int IN_F = 1024;
constexpr int OUT_F = 1024;
constexpr int M_TOT = 8 * 4096;   // 32768 tokens
constexpr int K_TOT = 1024;
constexpr int N_TOT = 1024;

// ---------------- kernel 1: unpack ternary weights (bit-plane permuted) -> int8 ----------------
__global__ __launch_bounds__(256) void unpack_kernel(
    const int* __restrict__ packed,
    int8_t* __restrict__ wt)           // [OUT_F][IN_F] int8 in {-1,0,1} (B^T layout)
{
    const int o = blockIdx.x;
    const int k0 = threadIdx.x * 4;
    const int sh = (o >> 8) * 2;
    const int pbase = ((o & 255) << 10) + k0;
    const int4 pw = *reinterpret_cast<const int4*>(packed + pbase);
    char4 r;
    r.x = (char)(((pw.x >> sh) & 3) - 1);
    r.y = (char)(((pw.y >> sh) & 3) - 1);
    r.z = (char)(((pw.z >> sh) & 3) - 1);
    r.w = (char)(((pw.w >> sh) & 3) - 1);
    *reinterpret_cast<char4*>(wt + (size_t)o * IN_F + k0) = r;
}

// ---------------- kernel 2: FUSED max + quantize-on-stage + int8 MFMA GEMM ----------------
// r16 GEMM core (256x256, BK=128, 8 waves 2Mx4N, dbuf, involution swizzle, plain stores).
// q never touches memory. REGISTER LEDGER (r17 spilled at 256+96): acc 128 AGPR;
// arch = aF 32 + bF 32 + xrA 32 + addr ~20 <= 128. Achieved by (a) no aG pre-read
// (Ph1 reuses aF; r13 measured the pre-read worth ~0.5us), (b) ONE live x-region
// buffer, alternately filled/drained:
//   end of iter T-1: xload(R0,T+1)           [8 vmem, crosses barrier in flight]
//   iter T: stageB(nxt,T+1); Ph0 MFMA; qwrite(nxt,R0) [auto-wait retires only xloads];
//           xload(R1,T+1); Ph1 MFMA; qwrite(nxt,R1); xload(R0,T+2);
//           lgkm(0); vmcnt(8) [certifies stageB, keeps xloads in flight]; barrier.
// Max-phase (r17-proven: conflicts 0, absmax exact): row absmax of own 256-row panel;
// 4 same-tm siblings XCD-adjacent -> L2 absorbs redundancy (FETCH 161MB measured).
// Quantize: (int)rintf(x*as) -- clamp provably dead (|x| <= a => |x*as| <= 127).
constexpr int BM = 256, BN = 256, BK = 128;
constexpr int NT = K_TOT / BK;   // 8

__global__ __launch_bounds__(512, 2) void fused_kernel(
    const float* __restrict__ x,
    const int8_t* __restrict__ wb,
    const float* __restrict__ wscale,
    const float* __restrict__ bias,
    float* __restrict__ out)
{
    // XCD-aware swizzle: nwg = 512, divisible by 8 -> bijective simple remap
    int bid = blockIdx.x;
    bid = (bid & 7) * ((int)gridDim.x >> 3) + (bid >> 3);
    const int tm = bid >> 2;            // 0..127
    const int tn = bid & 3;             // 0..3

    const int tid = threadIdx.x;
    const int lane = tid & 63;
    const int wid = tid >> 6;           // 0..7
    const int wr = wid >> 2;            // 0..1 (M half)
    const int wc = wid & 3;             // 0..3 (N quarter)

    __shared__ int8_t lds[2][2][2][128 * 128];  // [buf][ab][region] = 128 KiB
    __shared__ float sAs[256];
    __shared__ float sInv[256];

    const int rowA0 = tm * BM;
    const int rowB0 = tn * BN;
    const int frow = lane & 15;
    const int fq = lane >> 4;

    // ======== max-phase ========
    {
        const float wsc = wscale[0];
        const int c8 = lane & 7;
        #pragma unroll 1
        for (int pass = 0; pass < 4; ++pass) {
            const int lr = pass * 64 + wid * 8 + (lane >> 3);
            const float4* xr = reinterpret_cast<const float4*>(x + (size_t)(rowA0 + lr) * IN_F);
            float m = 0.f;
            #pragma unroll 8
            for (int j = 0; j < 32; ++j) {
                const float4 v = xr[c8 + 8 * j];
                m = fmaxf(m, fmaxf(fmaxf(fabsf(v.x), fabsf(v.y)),
                                   fmaxf(fabsf(v.z), fabsf(v.w))));
            }
            m = fmaxf(m, __shfl_xor(m, 1));
            m = fmaxf(m, __shfl_xor(m, 2));
            m = fmaxf(m, __shfl_xor(m, 4));
            if (c8 == 0) {
                const float a = fmaxf(m, 1e-5f);
                sAs[lr] = 127.0f / a;
                sInv[lr] = (a / 127.0f) * wsc;
            }
        }
    }
    __syncthreads();

    // ======== staging machinery ========
    const int rl0 = tid >> 3;           // 0..63
    const int cc = tid & 7;
    const int pz = cc ^ (rl0 & 7);      // swizzled write chunk (involution; 0-conflict r17)

    float asv[2][2];
    #pragma unroll
    for (int r = 0; r < 2; ++r)
        #pragma unroll
        for (int j = 0; j < 2; ++j)
            asv[r][j] = sAs[r * 64 + j * 128 + rl0];

    float4 xrA[2][4];                   // ONE live region (32 VGPR)
    auto xload = [&](int region, int kt) {
        #pragma unroll
        for (int j = 0; j < 2; ++j) {
            const float* src = x + (size_t)(rowA0 + region * 64 + j * 128 + rl0) * IN_F
                                 + kt * BK + cc * 16;
            #pragma unroll
            for (int u = 0; u < 4; ++u)
                xrA[j][u] = reinterpret_cast<const float4*>(src)[u];
        }
    };
    auto qwrite = [&](int buf, int region) {
        #pragma unroll
        for (int j = 0; j < 2; ++j) {
            const float as = asv[region][j];
            i32x4 o4;
            #pragma unroll
            for (int u = 0; u < 4; ++u) {
                const float4 v = xrA[j][u];
                const int b0 = (int)rintf(v.x * as) & 255;
                const int b1 = (int)rintf(v.y * as) & 255;
                const int b2 = (int)rintf(v.z * as) & 255;
                const int b3 = (int)rintf(v.w * as) & 255;
                o4[u] = b0 | (b1 << 8) | (b2 << 16) | (b3 << 24);
            }
            *reinterpret_cast<i32x4*>(
                &lds[buf][0][region][((j * 64 + rl0) * 8 + pz) * 16]) = o4;
        }
    };
    auto stageB = [&](int buf, int region, int kt) {
        #pragma unroll
        for (int j = 0; j < 2; ++j) {
            const int c = j * 512 + tid;
            const int rl = c >> 3, ccb = c & 7;
            const int grow = rowB0 + region * 128 + rl;
            const int scc = ccb ^ (rl & 7);
            const int8_t* src = wb + (size_t)grow * K_TOT + kt * BK + scc * 16;
            __builtin_amdgcn_global_load_lds(
                (const __attribute__((address_space(1))) void*)src,
                (__attribute__((address_space(3))) void*)&lds[buf][1][region][c * 16],
                16, 0, 0);
        }
    };

    auto ldA = [&](int buf, int region, int mf, int ks) -> i32x4 {
        const int local = wr * 64 + (mf & 3) * 16 + frow;
        const int ch = (ks * 4 + fq) ^ (local & 7);
        return *reinterpret_cast<const i32x4*>(&lds[buf][0][region][local * 128 + ch * 16]);
    };
    auto ldB = [&](int buf, int nf, int ks) -> i32x4 {
        const int region = wc >> 1;
        const int local = (wc & 1) * 64 + nf * 16 + frow;
        const int ch = (ks * 4 + fq) ^ (local & 7);
        return *reinterpret_cast<const i32x4*>(&lds[buf][1][region][local * 128 + ch * 16]);
    };

    i32x4 acc[8][4] = {};
    i32x4 aF[4][2], bF[4][2];

    // prologue: tile 0 -> buf 0; leave xload(R0,1) in flight across the barrier
    xload(0, 0);
    stageB(0, 0, 0); stageB(0, 1, 0);
    qwrite(0, 0);                        // auto-waits the 8 xloads (stageB stays)
    xload(1, 0);
    qwrite(0, 1);                        // auto-wait drains; prologue-only
    xload(0, 1);
    asm volatile("s_waitcnt lgkmcnt(0)" ::: "memory");
    __builtin_amdgcn_s_barrier();

    #pragma unroll 1
    for (int T = 0; T < NT; ++T) {
        const int cur = T & 1, nxt = cur ^ 1;
        const bool st = (T + 1 < NT);

        if (st) { stageB(nxt, 0, T + 1); stageB(nxt, 1, T + 1); }

        // ---- Ph0: read A-R0 + B; MFMA rows-lo (32)
        #pragma unroll
        for (int mf = 0; mf < 4; ++mf)
            #pragma unroll
            for (int ks = 0; ks < 2; ++ks)
                aF[mf][ks] = ldA(cur, 0, mf, ks);
        #pragma unroll
        for (int nf = 0; nf < 4; ++nf)
            #pragma unroll
            for (int ks = 0; ks < 2; ++ks)
                bF[nf][ks] = ldB(cur, nf, ks);
        asm volatile("s_waitcnt lgkmcnt(0)" ::: "memory");
        __builtin_amdgcn_sched_barrier(0);
        __builtin_amdgcn_s_setprio(1);
        #pragma unroll
        for (int mf = 0; mf < 4; ++mf)
            #pragma unroll
            for (int nf = 0; nf < 4; ++nf)
                #pragma unroll
                for (int ks = 0; ks < 2; ++ks)
                    acc[mf][nf] = __builtin_amdgcn_mfma_i32_16x16x64_i8(
                        aF[mf][ks], bF[nf][ks], acc[mf][nf], 0, 0, 0);
        __builtin_amdgcn_s_setprio(0);

        if (st) {
            qwrite(nxt, 0);              // xrA = x(R0,T+1), loaded end of iter T-1
            xload(1, T + 1);
        }

        // ---- Ph1: read A-R1 (reuse aF); MFMA rows-hi (32)
        #pragma unroll
        for (int mf = 0; mf < 4; ++mf)
            #pragma unroll
            for (int ks = 0; ks < 2; ++ks)
                aF[mf][ks] = ldA(cur, 1, mf, ks);
        asm volatile("s_waitcnt lgkmcnt(0)" ::: "memory");
        __builtin_amdgcn_sched_barrier(0);
        __builtin_amdgcn_s_setprio(1);
        #pragma unroll
        for (int mf = 0; mf < 4; ++mf)
            #pragma unroll
            for (int nf = 0; nf < 4; ++nf)
                #pragma unroll
                for (int ks = 0; ks < 2; ++ks)
                    acc[4 + mf][nf] = __builtin_amdgcn_mfma_i32_16x16x64_i8(
                        aF[mf][ks], bF[nf][ks], acc[4 + mf][nf], 0, 0, 0);
        __builtin_amdgcn_s_setprio(0);

        if (st) {
            qwrite(nxt, 1);              // xrA = x(R1,T+1), ~1 burst of latency cover
            if (T + 2 < NT) {
                xload(0, T + 2);
                asm volatile("s_waitcnt lgkmcnt(0)" ::: "memory");  // my ds_writes done
                asm volatile("s_waitcnt vmcnt(8)" ::: "memory");    // stageB certified; xloads fly
            } else {
                asm volatile("s_waitcnt lgkmcnt(0)" ::: "memory");
                asm volatile("s_waitcnt vmcnt(0)" ::: "memory");
            }
            __builtin_amdgcn_s_barrier();
        }
    }

    // epilogue: C/D 16x16 layout (col = lane&15, row = fq*4 + reg); plain stores.
    #pragma unroll
    for (int mi = 0; mi < 8; ++mi) {
        #pragma unroll
        for (int j = 0; j < 4; ++j) {
            const int lrow = wr * 128 + mi * 16 + fq * 4 + j;
            const int gm = rowA0 + lrow;
            const float sc = sInv[lrow];
            #pragma unroll
            for (int nf = 0; nf < 4; ++nf) {
                const int gn = rowB0 + wc * 64 + nf * 16 + frow;
                out[(size_t)gm * N_TOT + gn] = (float)acc[mi][nf][j] * sc + bias[gn];
            }
        }
    }
}

extern "C" void kernel_launch(void* const* d_in, const int* in_sizes, int n_in,
                              void* d_out, int out_size, void* d_ws, size_t ws_size,
                              hipStream_t stream) {
    const float* x = (const float*)d_in[0];
    const int* packed = (const int*)d_in[1];
    const float* wscale = (const float*)d_in[2];
    const float* bias = (const float*)d_in[3];
    float* out = (float*)d_out;

    int8_t* wt = (int8_t*)d_ws;   // 1 MiB unpacked ternary weights

    unpack_kernel<<<OUT_F, 256, 0, stream>>>(packed, wt);
    fused_kernel<<<(M_TOT / BM) * (N_TOT / BN), 512, 0, stream>>>(
        x, wt, wscale, bias, out);
}

// Round 19
// 109.908 us; speedup vs baseline: 1.8037x; 1.3296x over previous
//
#include <hip/hip_runtime.h>
#include <hip/hip_bf16.h>
#include <stdint.h>

typedef int i32x4 __attribute__((ext_vector_type(4)));

constexpr int IN_F = 1024;
constexpr int OUT_F = 1024;
constexpr int M_TOT = 8 * 4096;   // 32768 tokens
constexpr int K_TOT = 1024;
constexpr int N_TOT = 1024;

// ---------------- kernel 1: per-token int8 fake-quant (+ fused weight unpack) ----------------
__global__ __launch_bounds__(256) void quant_kernel(
    const float* __restrict__ x,
    const float* __restrict__ wscale,
    const int* __restrict__ packed,
    int8_t* __restrict__ q,            // [M_TOT][K_TOT] int8
    float* __restrict__ inv_row,       // [M_TOT]
    int8_t* __restrict__ wt)           // [OUT_F][IN_F] ternary int8 (B^T)
{
    const int row = blockIdx.x;
    const int t = threadIdx.x;
    const float4 v = reinterpret_cast<const float4*>(x + (size_t)row * IN_F)[t];
    float m = fmaxf(fmaxf(fabsf(v.x), fabsf(v.y)), fmaxf(fabsf(v.z), fabsf(v.w)));
    #pragma unroll
    for (int off = 32; off > 0; off >>= 1)
        m = fmaxf(m, __shfl_xor(m, off));
    __shared__ float smax[4];
    if ((t & 63) == 0) smax[t >> 6] = m;
    __syncthreads();
    m = fmaxf(fmaxf(smax[0], smax[1]), fmaxf(smax[2], smax[3]));
    const float a = fmaxf(m, 1e-5f);
    const float as = 127.0f / a;

    char4 o;
    o.x = (char)(int)fminf(fmaxf(rintf(v.x * as), -128.0f), 127.0f);
    o.y = (char)(int)fminf(fmaxf(rintf(v.y * as), -128.0f), 127.0f);
    o.z = (char)(int)fminf(fmaxf(rintf(v.z * as), -128.0f), 127.0f);
    o.w = (char)(int)fminf(fmaxf(rintf(v.w * as), -128.0f), 127.0f);
    reinterpret_cast<char4*>(q + (size_t)row * IN_F)[t] = o;
    if (t == 0) inv_row[row] = (a / 127.0f) * wscale[0];

    // fused unpack: blocks 0..1023 also expand one weight row (r5-verified mapping)
    if (row < OUT_F) {
        const int oo = row;
        const int k0 = t * 4;
        const int sh = (oo >> 8) * 2;
        const int pbase = ((oo & 255) << 10) + k0;
        const int4 pw = *reinterpret_cast<const int4*>(packed + pbase);
        char4 r;
        r.x = (char)(((pw.x >> sh) & 3) - 1);
        r.y = (char)(((pw.y >> sh) & 3) - 1);
        r.z = (char)(((pw.z >> sh) & 3) - 1);
        r.w = (char)(((pw.w >> sh) & 3) - 1);
        *reinterpret_cast<char4*>(wt + (size_t)oo * IN_F + k0) = r;
    }
}

// ---------------- kernel 2: int8 MFMA GEMM, r16 core, TILE-PAIRED ----------------
// 256x256, BK=128, 8 waves (2M x 4N), 128x64/wave, dbuf, involution swizzle, plain
// C stores (r16: nontemporal caused 131->185MB write amplification).
// NEW: grid 256 (1 block/CU, ONE round); each block runs TWO N-tiles sequentially
// (same tm -> A panel L2-hot). Tile-0's C-stores drain to HBM UNDER tile-1's K-loop
// (prologue vmcnt(0) only waits L2-accept) -> hides one of the two 10.4us/CU write
// drains that r16 exposed at round boundaries. Race audit: tile-1 stages buf 0,
// last read at tile-0 T=6 whose end-of-iter barrier ordered it; T=7 reads buf 1 only.
constexpr int BM = 256, BN = 256, BK = 128;
constexpr int NT = K_TOT / BK;   // 8

__global__ __launch_bounds__(512, 2) void gemm_kernel(
    const int8_t* __restrict__ qa,     // [M_TOT][K_TOT] int8
    const int8_t* __restrict__ wb,     // [N_TOT][K_TOT] int8
    const float* __restrict__ inv_row,
    const float* __restrict__ bias,
    float* __restrict__ out)
{
    // XCD-aware swizzle: nwg = 256, divisible by 8 -> bijective simple remap
    int bid = blockIdx.x;
    bid = (bid & 7) * ((int)gridDim.x >> 3) + (bid >> 3);
    const int tm = bid >> 1;            // 0..127
    const int tb = bid & 1;             // N pair: tiles tn = tb*2 + {0,1}

    const int tid = threadIdx.x;
    const int lane = tid & 63;
    const int wid = tid >> 6;           // 0..7
    const int wr = wid >> 2;            // 0..1 (M half)
    const int wc = wid & 3;             // 0..3 (N quarter)

    __shared__ int8_t lds[2][2][2][128 * 128];  // [buf][ab][region] = 128 KiB

    const int rowA0 = tm * BM;
    const int frow = lane & 15;
    const int fq = lane >> 4;

    #pragma unroll 1
    for (int tile = 0; tile < 2; ++tile) {
        const int rowB0 = (tb * 2 + tile) * BN;

        i32x4 acc[8][4] = {};

        auto stage = [&](int buf, int ab, int region, int kt) {
            const int8_t* base = ab ? wb : qa;
            #pragma unroll
            for (int j = 0; j < 2; ++j) {
                const int c = j * 512 + tid;
                const int rl = c >> 3, cc = c & 7;
                const int grow = ab ? (rowB0 + region * 128 + rl)
                                    : (rowA0 + (rl & 64) * 2 + region * 64 + (rl & 63));
                const int scc = cc ^ (rl & 7);
                const int8_t* src = base + (size_t)grow * K_TOT + kt * BK + scc * 16;
                __builtin_amdgcn_global_load_lds(
                    (const __attribute__((address_space(1))) void*)src,
                    (__attribute__((address_space(3))) void*)&lds[buf][ab][region][c * 16],
                    16, 0, 0);
            }
        };

        auto ldA = [&](int buf, int region, int mf, int ks) -> i32x4 {
            const int local = wr * 64 + (mf & 3) * 16 + frow;
            const int ch = (ks * 4 + fq) ^ (local & 7);
            return *reinterpret_cast<const i32x4*>(&lds[buf][0][region][local * 128 + ch * 16]);
        };
        auto ldB = [&](int buf, int nf, int ks) -> i32x4 {
            const int region = wc >> 1;
            const int local = (wc & 1) * 64 + nf * 16 + frow;
            const int ch = (ks * 4 + fq) ^ (local & 7);
            return *reinterpret_cast<const i32x4*>(&lds[buf][1][region][local * 128 + ch * 16]);
        };

        i32x4 aF[4][2], bF[4][2], aG[4][2];

        // prologue: stage tile0 (B then A), certify, barrier, pre-read Ph0(0)
        stage(0, 1, 0, 0); stage(0, 1, 1, 0); stage(0, 0, 0, 0); stage(0, 0, 1, 0);
        asm volatile("s_waitcnt vmcnt(0)" ::: "memory");
        __builtin_amdgcn_s_barrier();
        #pragma unroll
        for (int mf = 0; mf < 4; ++mf)
            #pragma unroll
            for (int ks = 0; ks < 2; ++ks)
                aF[mf][ks] = ldA(0, 0, mf, ks);
        #pragma unroll
        for (int nf = 0; nf < 4; ++nf)
            #pragma unroll
            for (int ks = 0; ks < 2; ++ks)
                bF[nf][ks] = ldB(0, nf, ks);
        // 16 ds_reads outstanding entering the loop

        #pragma unroll 1
        for (int T = 0; T < NT; ++T) {
            const int cur = T & 1, nxt = cur ^ 1;
            const bool st = (T + 1 < NT);

            // issue Ph1 reads (A-R1 -> aG) and all of tile T+1's staging
            #pragma unroll
            for (int mf = 0; mf < 4; ++mf)
                #pragma unroll
                for (int ks = 0; ks < 2; ++ks)
                    aG[mf][ks] = ldA(cur, 1, mf, ks);
            if (st) {
                stage(nxt, 1, 0, T + 1); stage(nxt, 1, 1, T + 1);
                stage(nxt, 0, 0, T + 1); stage(nxt, 0, 1, T + 1);
            }

            asm volatile("s_waitcnt lgkmcnt(8)" ::: "memory");   // Ph0 frags certified
            __builtin_amdgcn_sched_barrier(0);
            __builtin_amdgcn_s_setprio(1);
            #pragma unroll
            for (int mf = 0; mf < 4; ++mf)
                #pragma unroll
                for (int nf = 0; nf < 4; ++nf)
                    #pragma unroll
                    for (int ks = 0; ks < 2; ++ks)
                        acc[mf][nf] = __builtin_amdgcn_mfma_i32_16x16x64_i8(
                            aF[mf][ks], bF[nf][ks], acc[mf][nf], 0, 0, 0);
            __builtin_amdgcn_s_setprio(0);

            asm volatile("s_waitcnt lgkmcnt(0)" ::: "memory");   // Ph1 frags
            __builtin_amdgcn_sched_barrier(0);
            __builtin_amdgcn_s_setprio(1);
            #pragma unroll
            for (int mf = 0; mf < 4; ++mf)
                #pragma unroll
                for (int nf = 0; nf < 4; ++nf)
                    #pragma unroll
                    for (int ks = 0; ks < 2; ++ks)
                        acc[4 + mf][nf] = __builtin_amdgcn_mfma_i32_16x16x64_i8(
                            aG[mf][ks], bF[nf][ks], acc[4 + mf][nf], 0, 0, 0);
            __builtin_amdgcn_s_setprio(0);

            if (st) {
                asm volatile("s_waitcnt vmcnt(0)" ::: "memory"); // my T+1 stages landed
                __builtin_amdgcn_s_barrier();                    // everyone's landed
                // pre-read Ph0(T+1): A-R0 + B
                #pragma unroll
                for (int mf = 0; mf < 4; ++mf)
                    #pragma unroll
                    for (int ks = 0; ks < 2; ++ks)
                        aF[mf][ks] = ldA(nxt, 0, mf, ks);
                #pragma unroll
                for (int nf = 0; nf < 4; ++nf)
                    #pragma unroll
                    for (int ks = 0; ks < 2; ++ks)
                        bF[nf][ks] = ldB(nxt, nf, ks);
            }
        }

        // epilogue: C/D 16x16 layout (col = lane&15, row = fq*4 + reg); plain stores.
        // Stores issued, NOT waited: they drain under the next tile's K-loop.
        #pragma unroll
        for (int mi = 0; mi < 8; ++mi) {
            #pragma unroll
            for (int j = 0; j < 4; ++j) {
                const int gm = rowA0 + wr * 128 + mi * 16 + fq * 4 + j;
                const float sc = inv_row[gm];
                #pragma unroll
                for (int nf = 0; nf < 4; ++nf) {
                    const int gn = rowB0 + wc * 64 + nf * 16 + frow;
                    out[(size_t)gm * N_TOT + gn] = (float)acc[mi][nf][j] * sc + bias[gn];
                }
            }
        }
    }
}

extern "C" void kernel_launch(void* const* d_in, const int* in_sizes, int n_in,
                              void* d_out, int out_size, void* d_ws, size_t ws_size,
                              hipStream_t stream) {
    const float* x = (const float*)d_in[0];
    const int* packed = (const int*)d_in[1];
    const float* wscale = (const float*)d_in[2];
    const float* bias = (const float*)d_in[3];
    float* out = (float*)d_out;

    int8_t* q = (int8_t*)d_ws;                                          // 32 MiB
    int8_t* wt = (int8_t*)((char*)d_ws + (size_t)M_TOT * K_TOT);        // 1 MiB
    float* inv_row = (float*)((char*)d_ws + (size_t)M_TOT * K_TOT + (size_t)N_TOT * K_TOT);

    quant_kernel<<<M_TOT, 256, 0, stream>>>(x, wscale, packed, q, inv_row, wt);
    gemm_kernel<<<(M_TOT / BM) * (N_TOT / BN) / 2, 512, 0, stream>>>(q, wt, inv_row, bias, out);
}